// Round 12
// baseline (187.197 us; speedup 1.0000x reference)
//
#include <hip/hip_runtime.h>

typedef __attribute__((ext_vector_type(8))) short  short8;
typedef __attribute__((ext_vector_type(4))) float  f32x4;
typedef __attribute__((ext_vector_type(2))) float  f32x2;

#define CIN 32
#define COUT 32
#define DD 32
#define HH 48
#define WW 48
#define NTAP 27
#define SPATIAL (DD*HH*WW)          // 73728

// ---- ws layout (bytes): Bp2 (8KB/tap padded) | wpk (4KB/tap padded) | xT ----
#define BP2_BYTES (27*8192)                         // 221184
#define OFF_WPK   ((size_t)BP2_BYTES)
#define WPK_BYTES (27*4096)                         // 110592
#define OFF_XT    (OFF_WPK + WPK_BYTES)             // 331776 (16B aligned)
// xT bf16: 4,718,592 B -> total ~5.05 MB

#define SB0() __builtin_amdgcn_sched_barrier(0)
#define LGKM0_BAR() do { \
    asm volatile("s_waitcnt lgkmcnt(0)" ::: "memory"); \
    __builtin_amdgcn_s_barrier(); \
    SB0(); } while (0)

__device__ __forceinline__ unsigned short f2bf(float f) {
    union { float f; unsigned u; } v; v.f = f;
    unsigned r = v.u + 0x7FFFu + ((v.u >> 16) & 1u);   // RNE
    return (unsigned short)(r >> 16);
}
__device__ __forceinline__ float bitsf(unsigned u) {
    union { unsigned u; float f; } v; v.u = u; return v.f;
}

// ---------------------------------------------------------------- prep kernels
// conv B-pack, padded 8KB/tap: byte (n*8192 + (j*64+lane)*16 + e*2)
__global__ __launch_bounds__(256) void wprep2_kernel(
        const float* __restrict__ w_off, unsigned short* __restrict__ Bp2)
{
    int i = blockIdx.x * 256 + threadIdx.x;
    if (i >= 27 * 6 * 64 * 8) return;
    int e    = i & 7;
    int lane = (i >> 3) & 63;
    int j    = (i >> 9) % 6;
    int n    = i / (512 * 6);
    int col = lane & 15, kg = lane >> 4;
    int oc = j * 16 + col, c = kg * 8 + e;
    float v = (oc < 81) ? w_off[((size_t)oc * CIN + c) * NTAP + n] : 0.f;
    Bp2[(size_t)n * 4096 + (j * 64 + lane) * 8 + e] = f2bf(v);
}

// einsum B-pack, padded 4KB/tap: ush (n*2048 + (half*64+lane)*8 + e)
__global__ __launch_bounds__(256) void wdefprep_kernel(
        const float* __restrict__ w_def, unsigned short* __restrict__ wpk)
{
    int i = blockIdx.x * 256 + threadIdx.x;
    if (i >= 27 * 2 * 64 * 8) return;
    int e    = i & 7;
    int lane = (i >> 3) & 63;
    int half = (i >> 9) & 1;
    int n    = i >> 10;
    int kg = lane >> 4, col = lane & 15;
    int c  = kg * 8 + e, oc = half * 16 + col;
    wpk[(size_t)n * 2048 + (half * 64 + lane) * 8 + e] =
        f2bf(w_def[((size_t)oc * CIN + c) * NTAP + n]);
}

// x transpose: xT[pos][c] bf16
__global__ __launch_bounds__(256) void xtrans_kernel(
        const float* __restrict__ x, unsigned short* __restrict__ xT)
{
    __shared__ float t[CIN][65];
    const int p0 = blockIdx.x * 64;
    const int tid = threadIdx.x;
    const int tx = tid & 63, ty = tid >> 6;
    #pragma unroll
    for (int k = 0; k < 8; ++k) {
        int c = ty + k * 4;
        t[c][tx] = x[(size_t)c * SPATIAL + p0 + tx];
    }
    __syncthreads();
    const int pl = tid >> 2, cg = (tid & 3) * 8;
    short8 v;
    #pragma unroll
    for (int i = 0; i < 8; ++i) v[i] = (short)f2bf(t[cg + i][pl]);
    *(short8*)&xT[((size_t)(p0 + pl)) * 32 + cg] = v;
}

// ---------------------------------------------------------------- gather buf
struct Gath {
    uint4 cw[8];
    float gg[8];
};

__device__ __forceinline__ void tap_issue(
        Gath& tb, const uint4* __restrict__ Xu,
        float od, float oh, float ow,
        int n, int d, int h, int w, int kg)
{
    float rd = (float)(n / 9) - 1.f;
    float rh = (float)((n / 3) % 3) - 1.f;
    float rw = (float)(n % 3) - 1.f;

    float pdp = (float)(d + 1) + rd + od;
    float php = (float)(h + 1) + rh + oh;
    float pwp = (float)(w + 1) + rw + ow;

    float fd = floorf(pdp), fh = floorf(php), fw = floorf(pwp);
    float qd0 = fminf(fmaxf(fd,       0.f), 33.f);
    float qd1 = fminf(fmaxf(fd + 1.f, 0.f), 33.f);
    float qh0 = fminf(fmaxf(fh,       0.f), 49.f);
    float qh1 = fminf(fmaxf(fh + 1.f, 0.f), 49.f);
    float qw0 = fminf(fmaxf(fw,       0.f), 49.f);
    float qw1 = fminf(fmaxf(fw + 1.f, 0.f), 49.f);
    float pcd = fminf(fmaxf(pdp, 0.f), 33.f);
    float pch = fminf(fmaxf(php, 0.f), 49.f);
    float pcw = fminf(fmaxf(pwp, 0.f), 49.f);

    float gd0 = 1.f + (qd0 - pcd), gd1 = 1.f - (qd1 - pcd);
    float gh0 = 1.f + (qh0 - pch), gh1 = 1.f - (qh1 - pch);
    float gw0 = 1.f + (qw0 - pcw), gw1 = 1.f - (qw1 - pcw);
    // pad-corner semantics: zero per-axis gain, clamp index to real range
    gd0 = (qd0 >= 1.f && qd0 <= 32.f) ? gd0 : 0.f;
    gd1 = (qd1 >= 1.f && qd1 <= 32.f) ? gd1 : 0.f;
    gh0 = (qh0 >= 1.f && qh0 <= 48.f) ? gh0 : 0.f;
    gh1 = (qh1 >= 1.f && qh1 <= 48.f) ? gh1 : 0.f;
    gw0 = (qw0 >= 1.f && qw0 <= 48.f) ? gw0 : 0.f;
    gw1 = (qw1 >= 1.f && qw1 <= 48.f) ? gw1 : 0.f;
    int zd0 = (int)fminf(fmaxf(qd0, 1.f), 32.f) - 1;
    int zd1 = (int)fminf(fmaxf(qd1, 1.f), 32.f) - 1;
    int zh0 = (int)fminf(fmaxf(qh0, 1.f), 48.f) - 1;
    int zh1 = (int)fminf(fmaxf(qh1, 1.f), 48.f) - 1;
    int zw0 = (int)fminf(fmaxf(qw0, 1.f), 48.f) - 1;
    int zw1 = (int)fminf(fmaxf(qw1, 1.f), 48.f) - 1;

    int bd0 = zd0 * 2304, bd1 = zd1 * 2304;
    int bh0 = zh0 * 48,   bh1 = zh1 * 48;
    float gdh00 = gd0 * gh0, gdh01 = gd0 * gh1;
    float gdh10 = gd1 * gh0, gdh11 = gd1 * gh1;

    tb.cw[0] = Xu[(size_t)(bd0 + bh0 + zw0) * 4 + kg];
    tb.cw[1] = Xu[(size_t)(bd0 + bh0 + zw1) * 4 + kg];
    tb.cw[2] = Xu[(size_t)(bd0 + bh1 + zw0) * 4 + kg];
    tb.cw[3] = Xu[(size_t)(bd0 + bh1 + zw1) * 4 + kg];
    tb.cw[4] = Xu[(size_t)(bd1 + bh0 + zw0) * 4 + kg];
    tb.cw[5] = Xu[(size_t)(bd1 + bh0 + zw1) * 4 + kg];
    tb.cw[6] = Xu[(size_t)(bd1 + bh1 + zw0) * 4 + kg];
    tb.cw[7] = Xu[(size_t)(bd1 + bh1 + zw1) * 4 + kg];

    tb.gg[0] = gdh00 * gw0;  tb.gg[1] = gdh00 * gw1;
    tb.gg[2] = gdh01 * gw0;  tb.gg[3] = gdh01 * gw1;
    tb.gg[4] = gdh10 * gw0;  tb.gg[5] = gdh10 * gw1;
    tb.gg[6] = gdh11 * gw0;  tb.gg[7] = gdh11 * gw1;
}

__device__ __forceinline__ void tap_consume(
        const Gath& tb, short8 b0, short8 b1, f32x4& acc0, f32x4& acc1)
{
    f32x2 xa0 = {0.f, 0.f}, xa1 = {0.f, 0.f};
    f32x2 xa2 = {0.f, 0.f}, xa3 = {0.f, 0.f};

    #pragma unroll
    for (int e = 0; e < 8; ++e) {
        uint4 cw = tb.cw[e];
        f32x2 g2 = {tb.gg[e], tb.gg[e]};
        f32x2 v0 = {bitsf(cw.x << 16), bitsf(cw.x & 0xFFFF0000u)};
        f32x2 v1 = {bitsf(cw.y << 16), bitsf(cw.y & 0xFFFF0000u)};
        f32x2 v2 = {bitsf(cw.z << 16), bitsf(cw.z & 0xFFFF0000u)};
        f32x2 v3 = {bitsf(cw.w << 16), bitsf(cw.w & 0xFFFF0000u)};
        asm("v_pk_fma_f32 %0, %1, %2, %0" : "+v"(xa0) : "v"(v0), "v"(g2));
        asm("v_pk_fma_f32 %0, %1, %2, %0" : "+v"(xa1) : "v"(v1), "v"(g2));
        asm("v_pk_fma_f32 %0, %1, %2, %0" : "+v"(xa2) : "v"(v2), "v"(g2));
        asm("v_pk_fma_f32 %0, %1, %2, %0" : "+v"(xa3) : "v"(v3), "v"(g2));
    }

    union { unsigned u[4]; short8 s; } av;
    asm("v_cvt_pk_bf16_f32 %0, %1, %2" : "=v"(av.u[0]) : "v"(xa0.x), "v"(xa0.y));
    asm("v_cvt_pk_bf16_f32 %0, %1, %2" : "=v"(av.u[1]) : "v"(xa1.x), "v"(xa1.y));
    asm("v_cvt_pk_bf16_f32 %0, %1, %2" : "=v"(av.u[2]) : "v"(xa2.x), "v"(xa2.y));
    asm("v_cvt_pk_bf16_f32 %0, %1, %2" : "=v"(av.u[3]) : "v"(xa3.x), "v"(xa3.y));

    acc0 = __builtin_amdgcn_mfma_f32_16x16x32_bf16(av.s, b0, acc0, 0, 0, 0);
    acc1 = __builtin_amdgcn_mfma_f32_16x16x32_bf16(av.s, b1, acc1, 0, 0, 0);
}

// ---------------- Fused kernel with block-level LDS B-staging -----------------
// 4 waves / 64 pos per block. Per tap: every wave reg-loads its chunk of the
// tap's B-pack, ds_writes it, lgkmcnt(0)+s_barrier, then all waves consume
// B from LDS. B global traffic amortized 4x across the block.
__global__ __launch_bounds__(256, 3) void fused_deform7(
        const unsigned short* __restrict__ xT,    // [SPATIAL][32] bf16
        const unsigned short* __restrict__ Bp2,   // padded 8KB/tap
        const unsigned short* __restrict__ wpk,   // padded 4KB/tap
        float* __restrict__ out)                  // [32][SPATIAL] f32
{
    __shared__ float offl[4][16][97];                       // 24832 B (>=96 cols!)
    __shared__ __align__(16) char convB[2][8192];           // 16384 B
    __shared__ __align__(16) char ebuf[2][4096];            //  8192 B

    const int tid  = threadIdx.x;
    const int lane = tid & 63, wv = tid >> 6;
    const int p0   = blockIdx.x * 64 + wv * 16;
    const int kg   = lane >> 4;
    const int row  = lane & 15;
    const int pos  = p0 + row;
    const int w = pos % WW, h = (pos / WW) % HH, d = pos / (WW * HH);

    const uint4* Xu = (const uint4*)xT;
    const char*  Bb = (const char*)Bp2;
    const char*  Wb = (const char*)wpk;

    // ---------------- phase 1: offset conv with staged B ----------------
    f32x4 cacc[6];
    #pragma unroll
    for (int j = 0; j < 6; ++j) cacc[j] = (f32x4){0.f, 0.f, 0.f, 0.f};

    auto loadA = [&](int n, int& valid) -> uint4 {
        int td = n / 9, th = (n / 3) % 3, tw = n % 3;
        valid = ((unsigned)(d + td - 1) < DD)
              & ((unsigned)(h + th - 1) < HH)
              & ((unsigned)(w + tw - 1) < WW);
        int dpos = pos + (td - 1) * 2304 + (th - 1) * 48 + (tw - 1);
        int safe = valid ? dpos : pos;
        return Xu[(size_t)safe * 4 + kg];
    };
    auto loadBc = [&](int n, uint4* br) {
        const char* src = Bb + (size_t)n * 8192 + (wv * 2) * 1024 + lane * 16;
        br[0] = *(const uint4*)(src);
        br[1] = *(const uint4*)(src + 1024);
    };
    auto writeBc = [&](int buf, const uint4* br) {
        char* dst = &convB[buf][(wv * 2) * 1024 + lane * 16];
        *(uint4*)(dst)        = br[0];
        *(uint4*)(dst + 1024) = br[1];
    };
    auto consumeConv = [&](int buf, uint4 a, int valid) {
        if (!valid) { a.x = 0; a.y = 0; a.z = 0; a.w = 0; }
        union { uint4 u; short8 s; } av; av.u = a;
        #pragma unroll
        for (int j = 0; j < 6; ++j) {
            short8 b = *(const short8*)&convB[buf][(j * 64 + lane) * 16];
            cacc[j] = __builtin_amdgcn_mfma_f32_16x16x32_bf16(av.s, b, cacc[j], 0, 0, 0);
        }
    };

    {
        uint4 brA[2], brB[2], aA, aB;
        int vA, vB;
        loadBc(0, brA);  aA = loadA(0, vA);
        #pragma unroll 1
        for (int n = 0; n < 26; n += 2) {
            loadBc(n + 1, brB);  aB = loadA(n + 1, vB);
            SB0();
            writeBc(n & 1, brA);
            LGKM0_BAR();
            consumeConv(n & 1, aA, vA);
            loadBc(n + 2, brA);  aA = loadA(n + 2, vA);
            SB0();
            writeBc((n + 1) & 1, brB);
            LGKM0_BAR();
            consumeConv((n + 1) & 1, aB, vB);
        }
        SB0();
        writeBc(0, brA);                      // tap 26 (26&1 == 0)
        LGKM0_BAR();
        consumeConv(0, aA, vA);
    }

    // ---------------- phase 2: D-frags -> wave-local LDS ----------------
    #pragma unroll
    for (int j = 0; j < 6; ++j) {
        #pragma unroll
        for (int r = 0; r < 4; ++r)
            offl[wv][kg * 4 + r][j * 16 + row] = cacc[j][r];
    }
    __syncthreads();

    // ---------------- phase 3: deform gather + einsum, staged B ----------------
    const float* ol = &offl[wv][row][0];

    f32x4 acc0 = {0.f, 0.f, 0.f, 0.f};
    f32x4 acc1 = {0.f, 0.f, 0.f, 0.f};

    auto loadEB = [&](int n) -> uint4 {
        return *(const uint4*)(Wb + (size_t)n * 4096 + wv * 1024 + lane * 16);
    };
    auto writeEB = [&](int buf, uint4 v) {
        *(uint4*)&ebuf[buf][wv * 1024 + lane * 16] = v;
    };
    auto consumeTap = [&](int buf, const Gath& g) {
        short8 b0 = *(const short8*)&ebuf[buf][lane * 16];
        short8 b1 = *(const short8*)&ebuf[buf][1024 + lane * 16];
        tap_consume(g, b0, b1, acc0, acc1);
    };

    {
        Gath gA, gB;
        uint4 ebA, ebB;
        float odA = ol[0], ohA = ol[27], owA = ol[54];
        ebA = loadEB(0);
        tap_issue(gA, Xu, odA, ohA, owA, 0, d, h, w, kg);
        float odB = ol[1], ohB = ol[28], owB = ol[55];

        #pragma unroll 1
        for (int n = 0; n < 26; n += 2) {
            ebB = loadEB(n + 1);
            tap_issue(gB, Xu, odB, ohB, owB, n + 1, d, h, w, kg);
            odA = ol[n + 2]; ohA = ol[27 + n + 2]; owA = ol[54 + n + 2];
            SB0();
            writeEB(n & 1, ebA);
            LGKM0_BAR();
            consumeTap(n & 1, gA);
            ebA = loadEB(n + 2);
            tap_issue(gA, Xu, odA, ohA, owA, n + 2, d, h, w, kg);
            int nb = (n + 3 < 27) ? n + 3 : 26;
            odB = ol[nb]; ohB = ol[27 + nb]; owB = ol[54 + nb];
            SB0();
            writeEB((n + 1) & 1, ebB);
            LGKM0_BAR();
            consumeTap((n + 1) & 1, gB);
        }
        SB0();
        writeEB(0, ebA);                      // tap 26 (26&1 == 0)
        LGKM0_BAR();
        consumeTap(0, gA);
    }

    // D layout: col = lane&15 -> oc, row = kg*4+reg -> pos
    const int pb = p0 + kg * 4;
    *(f32x4*)&out[(size_t)row        * SPATIAL + pb] = acc0;
    *(f32x4*)&out[(size_t)(16 + row) * SPATIAL + pb] = acc1;
}

// ----------------------------------------------------------------------------
extern "C" void kernel_launch(void* const* d_in, const int* in_sizes, int n_in,
                              void* d_out, int out_size, void* d_ws, size_t ws_size,
                              hipStream_t stream)
{
    const float* x     = (const float*)d_in[0];
    const float* w_off = (const float*)d_in[1];
    const float* w_def = (const float*)d_in[2];
    float* out = (float*)d_out;

    unsigned short* Bp2 = (unsigned short*)((char*)d_ws);
    unsigned short* wpk = (unsigned short*)((char*)d_ws + OFF_WPK);
    unsigned short* xT  = (unsigned short*)((char*)d_ws + OFF_XT);

    wprep2_kernel<<<(27 * 6 * 64 * 8 + 255) / 256, 256, 0, stream>>>(w_off, Bp2);
    wdefprep_kernel<<<(27 * 2 * 64 * 8 + 255) / 256, 256, 0, stream>>>(w_def, wpk);
    xtrans_kernel<<<SPATIAL / 64, 256, 0, stream>>>(x, xT);
    fused_deform7<<<SPATIAL / 64, 256, 0, stream>>>(xT, Bp2, wpk, out);
}

// Round 13
// 132.663 us; speedup vs baseline: 1.4111x; 1.4111x over previous
//
#include <hip/hip_runtime.h>

typedef __attribute__((ext_vector_type(8))) short  short8;
typedef __attribute__((ext_vector_type(4))) float  f32x4;
typedef __attribute__((ext_vector_type(2))) float  f32x2;

#define CIN 32
#define COUT 32
#define DD 32
#define HH 48
#define WW 48
#define NTAP 27
#define SPATIAL (DD*HH*WW)          // 73728

// ---- ws layout (bytes) ----
#define BP2_ELEMS (27*6*64*8)                       // conv B-pack: 82944
#define OFF_WPK   ((size_t)BP2_ELEMS*2)             // 165888
#define WPK_ELEMS (27*2*64*8)                       // einsum B-pack: 27648
#define OFF_XT    (OFF_WPK + (size_t)WPK_ELEMS*2)   // 221184 (16B aligned)
// xT bf16: 4,718,592 B -> total ~4.94 MB

#define SB0() __builtin_amdgcn_sched_barrier(0)
#define SGB(mask, n) __builtin_amdgcn_sched_group_barrier((mask), (n), 0)
// masks: VALU=0x2, MFMA=0x8, VMEM_READ=0x20, DS_READ=0x100

__device__ __forceinline__ unsigned short f2bf(float f) {
    union { float f; unsigned u; } v; v.f = f;
    unsigned r = v.u + 0x7FFFu + ((v.u >> 16) & 1u);   // RNE
    return (unsigned short)(r >> 16);
}
__device__ __forceinline__ float bitsf(unsigned u) {
    union { unsigned u; float f; } v; v.u = u; return v.f;
}

// ---------------------------------------------------------------- prep kernels
// conv B-pack: Bp2[((n*6+j)*64+lane)*8+e] = bf16(w_off[j*16+col][kg*8+e][n])
__global__ __launch_bounds__(256) void wprep2_kernel(
        const float* __restrict__ w_off, unsigned short* __restrict__ Bp2)
{
    int i = blockIdx.x * 256 + threadIdx.x;
    if (i >= BP2_ELEMS) return;
    int e    = i & 7;
    int lane = (i >> 3) & 63;
    int j    = (i >> 9) % 6;
    int n    = i / (512 * 6);
    int col = lane & 15, kg = lane >> 4;
    int oc = j * 16 + col, c = kg * 8 + e;
    float v = (oc < 81) ? w_off[((size_t)oc * CIN + c) * NTAP + n] : 0.f;
    Bp2[i] = f2bf(v);
}

// einsum B-pack: wpk[((n*2+half)*64+lane)*8+e] = bf16(w_def[half*16+col][kg*8+e][n])
__global__ __launch_bounds__(256) void wdefprep_kernel(
        const float* __restrict__ w_def, unsigned short* __restrict__ wpk)
{
    int i = blockIdx.x * 256 + threadIdx.x;
    if (i >= WPK_ELEMS) return;
    int e    = i & 7;
    int lane = (i >> 3) & 63;
    int half = (i >> 9) & 1;
    int n    = i >> 10;
    int kg = lane >> 4, col = lane & 15;
    int c  = kg * 8 + e, oc = half * 16 + col;
    wpk[i] = f2bf(w_def[((size_t)oc * CIN + c) * NTAP + n]);
}

// x transpose: xT[pos][c] bf16 (coalesced read via LDS, 16B stores)
__global__ __launch_bounds__(256) void xtrans_kernel(
        const float* __restrict__ x, unsigned short* __restrict__ xT)
{
    __shared__ float t[CIN][65];
    const int p0 = blockIdx.x * 64;
    const int tid = threadIdx.x;
    const int tx = tid & 63, ty = tid >> 6;
    #pragma unroll
    for (int k = 0; k < 8; ++k) {
        int c = ty + k * 4;
        t[c][tx] = x[(size_t)c * SPATIAL + p0 + tx];
    }
    __syncthreads();
    const int pl = tid >> 2, cg = (tid & 3) * 8;
    short8 v;
    #pragma unroll
    for (int i = 0; i < 8; ++i) v[i] = (short)f2bf(t[cg + i][pl]);
    *(short8*)&xT[((size_t)(p0 + pl)) * 32 + cg] = v;
}

// ---------------------------------------------------------------- in-flight bufs
struct ConvT {
    uint4 a;
    uint4 wt[6];
    int   valid;
};

struct Gath {
    uint4 cw[8];
    uint4 wb0, wb1;
    float gg[8];
};

__device__ __forceinline__ void conv_issue(
        ConvT& ct, const uint4* __restrict__ Xu, const uint4* __restrict__ Bu,
        int n, int pos, int d, int h, int w, int kg, int lane)
{
    int td = n / 9, th = (n / 3) % 3, tw = n % 3;
    int valid = ((unsigned)(d + td - 1) < DD)
              & ((unsigned)(h + th - 1) < HH)
              & ((unsigned)(w + tw - 1) < WW);
    int dpos = pos + (td - 1) * 2304 + (th - 1) * 48 + (tw - 1);
    int safe = valid ? dpos : pos;                 // always in-bounds
    ct.a = Xu[(size_t)safe * 4 + kg];
    #pragma unroll
    for (int j = 0; j < 6; ++j)
        ct.wt[j] = Bu[(size_t)(n * 6 + j) * 64 + lane];
    ct.valid = valid;
}

__device__ __forceinline__ void conv_consume(const ConvT& ct, f32x4* cacc)
{
    uint4 a = ct.a;
    if (!ct.valid) { a.x = 0; a.y = 0; a.z = 0; a.w = 0; }
    union { uint4 u; short8 s; } av; av.u = a;
    #pragma unroll
    for (int j = 0; j < 6; ++j) {
        union { uint4 u; short8 s; } b; b.u = ct.wt[j];
        cacc[j] = __builtin_amdgcn_mfma_f32_16x16x32_bf16(av.s, b.s, cacc[j], 0, 0, 0);
    }
}

__device__ __forceinline__ void tap_issue(
        Gath& tb, const uint4* __restrict__ Xu, const uint4* __restrict__ Wu,
        float od, float oh, float ow,
        int n, int d, int h, int w, int kg, int lane)
{
    float rd = (float)(n / 9) - 1.f;
    float rh = (float)((n / 3) % 3) - 1.f;
    float rw = (float)(n % 3) - 1.f;

    float pdp = (float)(d + 1) + rd + od;
    float php = (float)(h + 1) + rh + oh;
    float pwp = (float)(w + 1) + rw + ow;

    float fd = floorf(pdp), fh = floorf(php), fw = floorf(pwp);
    float qd0 = fminf(fmaxf(fd,       0.f), 33.f);
    float qd1 = fminf(fmaxf(fd + 1.f, 0.f), 33.f);
    float qh0 = fminf(fmaxf(fh,       0.f), 49.f);
    float qh1 = fminf(fmaxf(fh + 1.f, 0.f), 49.f);
    float qw0 = fminf(fmaxf(fw,       0.f), 49.f);
    float qw1 = fminf(fmaxf(fw + 1.f, 0.f), 49.f);
    float pcd = fminf(fmaxf(pdp, 0.f), 33.f);
    float pch = fminf(fmaxf(php, 0.f), 49.f);
    float pcw = fminf(fmaxf(pwp, 0.f), 49.f);

    float gd0 = 1.f + (qd0 - pcd), gd1 = 1.f - (qd1 - pcd);
    float gh0 = 1.f + (qh0 - pch), gh1 = 1.f - (qh1 - pch);
    float gw0 = 1.f + (qw0 - pcw), gw1 = 1.f - (qw1 - pcw);
    // pad-corner semantics: zero per-axis gain, clamp index to real range
    gd0 = (qd0 >= 1.f && qd0 <= 32.f) ? gd0 : 0.f;
    gd1 = (qd1 >= 1.f && qd1 <= 32.f) ? gd1 : 0.f;
    gh0 = (qh0 >= 1.f && qh0 <= 48.f) ? gh0 : 0.f;
    gh1 = (qh1 >= 1.f && qh1 <= 48.f) ? gh1 : 0.f;
    gw0 = (qw0 >= 1.f && qw0 <= 48.f) ? gw0 : 0.f;
    gw1 = (qw1 >= 1.f && qw1 <= 48.f) ? gw1 : 0.f;
    int zd0 = (int)fminf(fmaxf(qd0, 1.f), 32.f) - 1;
    int zd1 = (int)fminf(fmaxf(qd1, 1.f), 32.f) - 1;
    int zh0 = (int)fminf(fmaxf(qh0, 1.f), 48.f) - 1;
    int zh1 = (int)fminf(fmaxf(qh1, 1.f), 48.f) - 1;
    int zw0 = (int)fminf(fmaxf(qw0, 1.f), 48.f) - 1;
    int zw1 = (int)fminf(fmaxf(qw1, 1.f), 48.f) - 1;

    int bd0 = zd0 * 2304, bd1 = zd1 * 2304;
    int bh0 = zh0 * 48,   bh1 = zh1 * 48;
    float gdh00 = gd0 * gh0, gdh01 = gd0 * gh1;
    float gdh10 = gd1 * gh0, gdh11 = gd1 * gh1;

    tb.cw[0] = Xu[(size_t)(bd0 + bh0 + zw0) * 4 + kg];
    tb.cw[1] = Xu[(size_t)(bd0 + bh0 + zw1) * 4 + kg];
    tb.cw[2] = Xu[(size_t)(bd0 + bh1 + zw0) * 4 + kg];
    tb.cw[3] = Xu[(size_t)(bd0 + bh1 + zw1) * 4 + kg];
    tb.cw[4] = Xu[(size_t)(bd1 + bh0 + zw0) * 4 + kg];
    tb.cw[5] = Xu[(size_t)(bd1 + bh0 + zw1) * 4 + kg];
    tb.cw[6] = Xu[(size_t)(bd1 + bh1 + zw0) * 4 + kg];
    tb.cw[7] = Xu[(size_t)(bd1 + bh1 + zw1) * 4 + kg];
    tb.wb0   = Wu[(size_t)(n * 2 + 0) * 64 + lane];
    tb.wb1   = Wu[(size_t)(n * 2 + 1) * 64 + lane];

    tb.gg[0] = gdh00 * gw0;  tb.gg[1] = gdh00 * gw1;
    tb.gg[2] = gdh01 * gw0;  tb.gg[3] = gdh01 * gw1;
    tb.gg[4] = gdh10 * gw0;  tb.gg[5] = gdh10 * gw1;
    tb.gg[6] = gdh11 * gw0;  tb.gg[7] = gdh11 * gw1;
}

__device__ __forceinline__ void tap_consume(
        const Gath& tb, f32x4& acc0, f32x4& acc1)
{
    f32x2 xa0 = {0.f, 0.f}, xa1 = {0.f, 0.f};
    f32x2 xa2 = {0.f, 0.f}, xa3 = {0.f, 0.f};

    #pragma unroll
    for (int e = 0; e < 8; ++e) {
        uint4 cw = tb.cw[e];
        f32x2 g2 = {tb.gg[e], tb.gg[e]};
        f32x2 v0 = {bitsf(cw.x << 16), bitsf(cw.x & 0xFFFF0000u)};
        f32x2 v1 = {bitsf(cw.y << 16), bitsf(cw.y & 0xFFFF0000u)};
        f32x2 v2 = {bitsf(cw.z << 16), bitsf(cw.z & 0xFFFF0000u)};
        f32x2 v3 = {bitsf(cw.w << 16), bitsf(cw.w & 0xFFFF0000u)};
        asm("v_pk_fma_f32 %0, %1, %2, %0" : "+v"(xa0) : "v"(v0), "v"(g2));
        asm("v_pk_fma_f32 %0, %1, %2, %0" : "+v"(xa1) : "v"(v1), "v"(g2));
        asm("v_pk_fma_f32 %0, %1, %2, %0" : "+v"(xa2) : "v"(v2), "v"(g2));
        asm("v_pk_fma_f32 %0, %1, %2, %0" : "+v"(xa3) : "v"(v3), "v"(g2));
    }

    union { unsigned u[4]; short8 s; } av;
    asm("v_cvt_pk_bf16_f32 %0, %1, %2" : "=v"(av.u[0]) : "v"(xa0.x), "v"(xa0.y));
    asm("v_cvt_pk_bf16_f32 %0, %1, %2" : "=v"(av.u[1]) : "v"(xa1.x), "v"(xa1.y));
    asm("v_cvt_pk_bf16_f32 %0, %1, %2" : "=v"(av.u[2]) : "v"(xa2.x), "v"(xa2.y));
    asm("v_cvt_pk_bf16_f32 %0, %1, %2" : "=v"(av.u[3]) : "v"(xa3.x), "v"(xa3.y));

    union { uint4 u; short8 s; } b0, b1;
    b0.u = tb.wb0; b1.u = tb.wb1;
    acc0 = __builtin_amdgcn_mfma_f32_16x16x32_bf16(av.s, b0.s, acc0, 0, 0, 0);
    acc1 = __builtin_amdgcn_mfma_f32_16x16x32_bf16(av.s, b1.s, acc1, 0, 0, 0);
}

// ---------------- Fused kernel: offset conv (MFMA) -> LDS -> deform (MFMA)
// 2-wave blocks (32 pos). XCD-swizzled blockIdx (590KB xT slab per XCD L2).
// sched_group_barrier sequences direct the scheduler to cluster each
// iteration as [addr VALU][10 VMEM reads][consume VALU][MFMA].
__global__ __launch_bounds__(128, 3) void fused_deform8(
        const unsigned short* __restrict__ xT,    // [SPATIAL][32] bf16
        const unsigned short* __restrict__ Bp2,
        const unsigned short* __restrict__ wpk,
        float* __restrict__ out)                  // [32][SPATIAL] f32
{
    __shared__ float offl[2][16][97];             // 12.4 KB

    // bijective XCD swizzle: 2304 blocks, 8 XCDs, 288 contiguous blocks each
    const int bid  = (int)blockIdx.x;
    const int sbid = (bid & 7) * 288 + (bid >> 3);

    const int tid  = threadIdx.x;
    const int lane = tid & 63, wv = tid >> 6;
    const int p0   = sbid * 32 + wv * 16;
    const int kg   = lane >> 4;
    const int row  = lane & 15;
    const int pos  = p0 + row;
    const int w = pos % WW, h = (pos / WW) % HH, d = pos / (WW * HH);

    const uint4* Xu = (const uint4*)xT;
    const uint4* Bu = (const uint4*)Bp2;
    const uint4* Wu = (const uint4*)wpk;

    // ---------------- phase 1: offset conv, 2-deep pipelined ----------------
    f32x4 cacc[6];
    #pragma unroll
    for (int j = 0; j < 6; ++j) cacc[j] = (f32x4){0.f, 0.f, 0.f, 0.f};

    {
        ConvT cA, cB;
        conv_issue(cA, Xu, Bu, 0, pos, d, h, w, kg, lane);
        SB0();
        #pragma unroll 1
        for (int n = 0; n < 26; n += 2) {
            conv_issue(cB, Xu, Bu, n + 1, pos, d, h, w, kg, lane);
            conv_consume(cA, cacc);
            SGB(0x2, 16); SGB(0x20, 7); SGB(0x2, 8); SGB(0x8, 6);
            SB0();
            conv_issue(cA, Xu, Bu, n + 2, pos, d, h, w, kg, lane);
            conv_consume(cB, cacc);
            SGB(0x2, 16); SGB(0x20, 7); SGB(0x2, 8); SGB(0x8, 6);
            SB0();
        }
        conv_consume(cA, cacc);                   // tap 26
    }

    // ---------------- phase 2: D-frags -> wave-local LDS ----------------
    #pragma unroll
    for (int j = 0; j < 6; ++j) {
        #pragma unroll
        for (int r = 0; r < 4; ++r)
            offl[wv][kg * 4 + r][j * 16 + row] = cacc[j][r];
    }
    __syncthreads();

    // ---------------- phase 3: pipelined deform gather + einsum ----------------
    const float* ol = &offl[wv][row][0];

    f32x4 acc0 = {0.f, 0.f, 0.f, 0.f};
    f32x4 acc1 = {0.f, 0.f, 0.f, 0.f};

    {
        Gath gA, gB;
        float odA = ol[0], ohA = ol[27], owA = ol[54];
        tap_issue(gA, Xu, Wu, odA, ohA, owA, 0, d, h, w, kg, lane);
        SB0();
        float odB = ol[1], ohB = ol[28], owB = ol[55];

        #pragma unroll 1
        for (int n = 0; n < 26; n += 2) {
            tap_issue(gB, Xu, Wu, odB, ohB, owB, n + 1, d, h, w, kg, lane);
            odA = ol[n + 2]; ohA = ol[27 + n + 2]; owA = ol[54 + n + 2];
            tap_consume(gA, acc0, acc1);
            SGB(0x2, 64); SGB(0x20, 10); SGB(0x2, 104); SGB(0x8, 2);
            SB0();
            tap_issue(gA, Xu, Wu, odA, ohA, owA, n + 2, d, h, w, kg, lane);
            int nb = (n + 3 < 27) ? n + 3 : 26;
            odB = ol[nb]; ohB = ol[27 + nb]; owB = ol[54 + nb];
            tap_consume(gB, acc0, acc1);
            SGB(0x2, 64); SGB(0x20, 10); SGB(0x2, 104); SGB(0x8, 2);
            SB0();
        }
        tap_consume(gA, acc0, acc1);              // tap 26
    }

    // D layout: col = lane&15 -> oc, row = kg*4+reg -> pos
    const int pb = p0 + kg * 4;
    *(f32x4*)&out[(size_t)row        * SPATIAL + pb] = acc0;
    *(f32x4*)&out[(size_t)(16 + row) * SPATIAL + pb] = acc1;
}

// ----------------------------------------------------------------------------
extern "C" void kernel_launch(void* const* d_in, const int* in_sizes, int n_in,
                              void* d_out, int out_size, void* d_ws, size_t ws_size,
                              hipStream_t stream)
{
    const float* x     = (const float*)d_in[0];
    const float* w_off = (const float*)d_in[1];
    const float* w_def = (const float*)d_in[2];
    float* out = (float*)d_out;

    unsigned short* Bp2 = (unsigned short*)((char*)d_ws);
    unsigned short* wpk = (unsigned short*)((char*)d_ws + OFF_WPK);
    unsigned short* xT  = (unsigned short*)((char*)d_ws + OFF_XT);

    wprep2_kernel<<<(BP2_ELEMS + 255) / 256, 256, 0, stream>>>(w_off, Bp2);
    wdefprep_kernel<<<(WPK_ELEMS + 255) / 256, 256, 0, stream>>>(w_def, wpk);
    xtrans_kernel<<<SPATIAL / 64, 256, 0, stream>>>(x, xT);
    fused_deform8<<<SPATIAL / 32, 128, 0, stream>>>(xT, Bp2, wpk, out);
}

// Round 14
// 123.912 us; speedup vs baseline: 1.5107x; 1.0706x over previous
//
#include <hip/hip_runtime.h>

typedef __attribute__((ext_vector_type(8))) short  short8;
typedef __attribute__((ext_vector_type(4))) float  f32x4;
typedef __attribute__((ext_vector_type(2))) float  f32x2;

#define CIN 32
#define COUT 32
#define DD 32
#define HH 48
#define WW 48
#define NTAP 27
#define SPATIAL (DD*HH*WW)          // 73728

// ---- ws layout (bytes) ----
#define BP2_ELEMS (27*6*64*8)                       // conv B-pack: 82944
#define OFF_WPK   ((size_t)BP2_ELEMS*2)             // 165888
#define WPK_ELEMS (27*2*64*8)                       // einsum B-pack: 27648
#define OFF_XT    (OFF_WPK + (size_t)WPK_ELEMS*2)   // 221184 (16B aligned)
// xT bf16: 4,718,592 B -> total ~4.94 MB

#define SB0() __builtin_amdgcn_sched_barrier(0)

__device__ __forceinline__ unsigned short f2bf(float f) {
    union { float f; unsigned u; } v; v.f = f;
    unsigned r = v.u + 0x7FFFu + ((v.u >> 16) & 1u);   // RNE
    return (unsigned short)(r >> 16);
}
__device__ __forceinline__ float bitsf(unsigned u) {
    union { unsigned u; float f; } v; v.u = u; return v.f;
}

// ---------------------------------------------------------------- prep kernels
// conv B-pack: Bp2[((n*6+j)*64+lane)*8+e] = bf16(w_off[j*16+col][kg*8+e][n])
__global__ __launch_bounds__(256) void wprep2_kernel(
        const float* __restrict__ w_off, unsigned short* __restrict__ Bp2)
{
    int i = blockIdx.x * 256 + threadIdx.x;
    if (i >= BP2_ELEMS) return;
    int e    = i & 7;
    int lane = (i >> 3) & 63;
    int j    = (i >> 9) % 6;
    int n    = i / (512 * 6);
    int col = lane & 15, kg = lane >> 4;
    int oc = j * 16 + col, c = kg * 8 + e;
    float v = (oc < 81) ? w_off[((size_t)oc * CIN + c) * NTAP + n] : 0.f;
    Bp2[i] = f2bf(v);
}

// einsum B-pack: wpk[((n*2+half)*64+lane)*8+e] = bf16(w_def[half*16+col][kg*8+e][n])
__global__ __launch_bounds__(256) void wdefprep_kernel(
        const float* __restrict__ w_def, unsigned short* __restrict__ wpk)
{
    int i = blockIdx.x * 256 + threadIdx.x;
    if (i >= WPK_ELEMS) return;
    int e    = i & 7;
    int lane = (i >> 3) & 63;
    int half = (i >> 9) & 1;
    int n    = i >> 10;
    int kg = lane >> 4, col = lane & 15;
    int c  = kg * 8 + e, oc = half * 16 + col;
    wpk[i] = f2bf(w_def[((size_t)oc * CIN + c) * NTAP + n]);
}

// x transpose: xT[pos][c] bf16 (coalesced read via LDS, 16B stores)
__global__ __launch_bounds__(256) void xtrans_kernel(
        const float* __restrict__ x, unsigned short* __restrict__ xT)
{
    __shared__ float t[CIN][65];
    const int p0 = blockIdx.x * 64;
    const int tid = threadIdx.x;
    const int tx = tid & 63, ty = tid >> 6;
    #pragma unroll
    for (int k = 0; k < 8; ++k) {
        int c = ty + k * 4;
        t[c][tx] = x[(size_t)c * SPATIAL + p0 + tx];
    }
    __syncthreads();
    const int pl = tid >> 2, cg = (tid & 3) * 8;
    short8 v;
    #pragma unroll
    for (int i = 0; i < 8; ++i) v[i] = (short)f2bf(t[cg + i][pl]);
    *(short8*)&xT[((size_t)(p0 + pl)) * 32 + cg] = v;
}

// ---------------------------------------------------------------- gather buf
struct Gath {
    uint4 cw[8];
    float gg[8];
};

__device__ __forceinline__ void tap_issue(
        Gath& tb, const uint4* __restrict__ Xu,
        float od, float oh, float ow,
        int n, int d, int h, int w, int kg)
{
    float rd = (float)(n / 9) - 1.f;
    float rh = (float)((n / 3) % 3) - 1.f;
    float rw = (float)(n % 3) - 1.f;

    float pdp = (float)(d + 1) + rd + od;
    float php = (float)(h + 1) + rh + oh;
    float pwp = (float)(w + 1) + rw + ow;

    float fd = floorf(pdp), fh = floorf(php), fw = floorf(pwp);
    float qd0 = fminf(fmaxf(fd,       0.f), 33.f);
    float qd1 = fminf(fmaxf(fd + 1.f, 0.f), 33.f);
    float qh0 = fminf(fmaxf(fh,       0.f), 49.f);
    float qh1 = fminf(fmaxf(fh + 1.f, 0.f), 49.f);
    float qw0 = fminf(fmaxf(fw,       0.f), 49.f);
    float qw1 = fminf(fmaxf(fw + 1.f, 0.f), 49.f);
    float pcd = fminf(fmaxf(pdp, 0.f), 33.f);
    float pch = fminf(fmaxf(php, 0.f), 49.f);
    float pcw = fminf(fmaxf(pwp, 0.f), 49.f);

    float gd0 = 1.f + (qd0 - pcd), gd1 = 1.f - (qd1 - pcd);
    float gh0 = 1.f + (qh0 - pch), gh1 = 1.f - (qh1 - pch);
    float gw0 = 1.f + (qw0 - pcw), gw1 = 1.f - (qw1 - pcw);
    // pad-corner semantics: zero per-axis gain, clamp index to real range
    gd0 = (qd0 >= 1.f && qd0 <= 32.f) ? gd0 : 0.f;
    gd1 = (qd1 >= 1.f && qd1 <= 32.f) ? gd1 : 0.f;
    gh0 = (qh0 >= 1.f && qh0 <= 48.f) ? gh0 : 0.f;
    gh1 = (qh1 >= 1.f && qh1 <= 48.f) ? gh1 : 0.f;
    gw0 = (qw0 >= 1.f && qw0 <= 48.f) ? gw0 : 0.f;
    gw1 = (qw1 >= 1.f && qw1 <= 48.f) ? gw1 : 0.f;
    int zd0 = (int)fminf(fmaxf(qd0, 1.f), 32.f) - 1;
    int zd1 = (int)fminf(fmaxf(qd1, 1.f), 32.f) - 1;
    int zh0 = (int)fminf(fmaxf(qh0, 1.f), 48.f) - 1;
    int zh1 = (int)fminf(fmaxf(qh1, 1.f), 48.f) - 1;
    int zw0 = (int)fminf(fmaxf(qw0, 1.f), 48.f) - 1;
    int zw1 = (int)fminf(fmaxf(qw1, 1.f), 48.f) - 1;

    int bd0 = zd0 * 2304, bd1 = zd1 * 2304;
    int bh0 = zh0 * 48,   bh1 = zh1 * 48;
    float gdh00 = gd0 * gh0, gdh01 = gd0 * gh1;
    float gdh10 = gd1 * gh0, gdh11 = gd1 * gh1;

    tb.cw[0] = Xu[(size_t)(bd0 + bh0 + zw0) * 4 + kg];
    tb.cw[1] = Xu[(size_t)(bd0 + bh0 + zw1) * 4 + kg];
    tb.cw[2] = Xu[(size_t)(bd0 + bh1 + zw0) * 4 + kg];
    tb.cw[3] = Xu[(size_t)(bd0 + bh1 + zw1) * 4 + kg];
    tb.cw[4] = Xu[(size_t)(bd1 + bh0 + zw0) * 4 + kg];
    tb.cw[5] = Xu[(size_t)(bd1 + bh0 + zw1) * 4 + kg];
    tb.cw[6] = Xu[(size_t)(bd1 + bh1 + zw0) * 4 + kg];
    tb.cw[7] = Xu[(size_t)(bd1 + bh1 + zw1) * 4 + kg];

    tb.gg[0] = gdh00 * gw0;  tb.gg[1] = gdh00 * gw1;
    tb.gg[2] = gdh01 * gw0;  tb.gg[3] = gdh01 * gw1;
    tb.gg[4] = gdh10 * gw0;  tb.gg[5] = gdh10 * gw1;
    tb.gg[6] = gdh11 * gw0;  tb.gg[7] = gdh11 * gw1;
}

__device__ __forceinline__ void tap_consume(
        const Gath& tb, short8 b0, short8 b1, f32x4& acc0, f32x4& acc1)
{
    f32x2 xa0 = {0.f, 0.f}, xa1 = {0.f, 0.f};
    f32x2 xa2 = {0.f, 0.f}, xa3 = {0.f, 0.f};

    #pragma unroll
    for (int e = 0; e < 8; ++e) {
        uint4 cw = tb.cw[e];
        f32x2 g2 = {tb.gg[e], tb.gg[e]};
        f32x2 v0 = {bitsf(cw.x << 16), bitsf(cw.x & 0xFFFF0000u)};
        f32x2 v1 = {bitsf(cw.y << 16), bitsf(cw.y & 0xFFFF0000u)};
        f32x2 v2 = {bitsf(cw.z << 16), bitsf(cw.z & 0xFFFF0000u)};
        f32x2 v3 = {bitsf(cw.w << 16), bitsf(cw.w & 0xFFFF0000u)};
        asm("v_pk_fma_f32 %0, %1, %2, %0" : "+v"(xa0) : "v"(v0), "v"(g2));
        asm("v_pk_fma_f32 %0, %1, %2, %0" : "+v"(xa1) : "v"(v1), "v"(g2));
        asm("v_pk_fma_f32 %0, %1, %2, %0" : "+v"(xa2) : "v"(v2), "v"(g2));
        asm("v_pk_fma_f32 %0, %1, %2, %0" : "+v"(xa3) : "v"(v3), "v"(g2));
    }

    union { unsigned u[4]; short8 s; } av;
    asm("v_cvt_pk_bf16_f32 %0, %1, %2" : "=v"(av.u[0]) : "v"(xa0.x), "v"(xa0.y));
    asm("v_cvt_pk_bf16_f32 %0, %1, %2" : "=v"(av.u[1]) : "v"(xa1.x), "v"(xa1.y));
    asm("v_cvt_pk_bf16_f32 %0, %1, %2" : "=v"(av.u[2]) : "v"(xa2.x), "v"(xa2.y));
    asm("v_cvt_pk_bf16_f32 %0, %1, %2" : "=v"(av.u[3]) : "v"(xa3.x), "v"(xa3.y));

    acc0 = __builtin_amdgcn_mfma_f32_16x16x32_bf16(av.s, b0, acc0, 0, 0, 0);
    acc1 = __builtin_amdgcn_mfma_f32_16x16x32_bf16(av.s, b1, acc1, 0, 0, 0);
}

// ---------------- Fused kernel, M=2 tiles/wave (B-fragment register reuse)
// Wave owns 32 positions (2 M16 tiles). Conv-B (6 frags/tap) and einsum-B
// (2 frags/tap) loaded ONCE per wave per tap, feeding both tiles' MFMAs —
// halves the B-side L1 line probes vs one-tile waves. XCD-swizzled blocks.
__global__ __launch_bounds__(128, 2) void fused_deform9(
        const unsigned short* __restrict__ xT,    // [SPATIAL][32] bf16
        const unsigned short* __restrict__ Bp2,
        const unsigned short* __restrict__ wpk,
        float* __restrict__ out)                  // [32][SPATIAL] f32
{
    __shared__ float offl[2][2][16][82];          // 21 KB (cols 0..80 read)

    // bijective XCD swizzle: 1152 blocks = 8 XCDs x 144 contiguous
    const int bid  = (int)blockIdx.x;
    const int sbid = (bid & 7) * 144 + (bid >> 3);

    const int tid  = threadIdx.x;
    const int lane = tid & 63, wv = tid >> 6;
    const int p0   = sbid * 64 + wv * 32;
    const int kg   = lane >> 4;
    const int row  = lane & 15;
    const int pos0 = p0 + row;
    const int pos1 = p0 + 16 + row;
    const int w0c = pos0 % WW, h0c = (pos0 / WW) % HH, d0c = pos0 / (WW * HH);
    const int w1c = pos1 % WW, h1c = (pos1 / WW) % HH, d1c = pos1 / (WW * HH);

    const uint4* Xu = (const uint4*)xT;
    const uint4* Bu = (const uint4*)Bp2;
    const uint4* Wu = (const uint4*)wpk;

    // ---------------- phase 1: offset conv, B shared across 2 tiles ----------
    f32x4 cacc0[6], cacc1[6];
    #pragma unroll
    for (int j = 0; j < 6; ++j) {
        cacc0[j] = (f32x4){0.f, 0.f, 0.f, 0.f};
        cacc1[j] = (f32x4){0.f, 0.f, 0.f, 0.f};
    }

    {
        #pragma unroll 1
        for (int n = 0; n < NTAP; ++n) {
            int td = n / 9, th = (n / 3) % 3, tw = n % 3;
            int dis = (td - 1) * 2304 + (th - 1) * 48 + (tw - 1);
            int v0 = ((unsigned)(d0c + td - 1) < DD) & ((unsigned)(h0c + th - 1) < HH)
                   & ((unsigned)(w0c + tw - 1) < WW);
            int v1 = ((unsigned)(d1c + td - 1) < DD) & ((unsigned)(h1c + th - 1) < HH)
                   & ((unsigned)(w1c + tw - 1) < WW);
            uint4 a0 = Xu[(size_t)(v0 ? pos0 + dis : pos0) * 4 + kg];
            uint4 a1 = Xu[(size_t)(v1 ? pos1 + dis : pos1) * 4 + kg];
            uint4 wt[6];
            #pragma unroll
            for (int j = 0; j < 6; ++j)
                wt[j] = Bu[(size_t)(n * 6 + j) * 64 + lane];
            SB0();
            if (!v0) { a0.x = 0; a0.y = 0; a0.z = 0; a0.w = 0; }
            if (!v1) { a1.x = 0; a1.y = 0; a1.z = 0; a1.w = 0; }
            union { uint4 u; short8 s; } av0, av1, b;
            av0.u = a0; av1.u = a1;
            #pragma unroll
            for (int j = 0; j < 6; ++j) {
                b.u = wt[j];
                cacc0[j] = __builtin_amdgcn_mfma_f32_16x16x32_bf16(av0.s, b.s, cacc0[j], 0, 0, 0);
                cacc1[j] = __builtin_amdgcn_mfma_f32_16x16x32_bf16(av1.s, b.s, cacc1[j], 0, 0, 0);
            }
        }
    }

    // ---------------- phase 2: D-frags -> wave-local LDS ----------------
    // col = j*16+row (only cols < 81 are ever read; col 81..95 are zero-pad)
    #pragma unroll
    for (int j = 0; j < 6; ++j) {
        #pragma unroll
        for (int r = 0; r < 4; ++r) {
            int col = j * 16 + row;
            if (col < 81) {
                offl[wv][0][kg * 4 + r][col] = cacc0[j][r];
                offl[wv][1][kg * 4 + r][col] = cacc1[j][r];
            }
        }
    }
    __syncthreads();

    // ---------------- phase 3: gather + einsum, B shared across 2 tiles -------
    const float* ol0 = &offl[wv][0][row][0];
    const float* ol1 = &offl[wv][1][row][0];

    f32x4 acc00 = {0.f, 0.f, 0.f, 0.f}, acc01 = {0.f, 0.f, 0.f, 0.f};
    f32x4 acc10 = {0.f, 0.f, 0.f, 0.f}, acc11 = {0.f, 0.f, 0.f, 0.f};

    {
        Gath g0, g1;
        #pragma unroll 1
        for (int n = 0; n < NTAP; ++n) {
            uint4 wbu0 = Wu[(size_t)(n * 2 + 0) * 64 + lane];
            uint4 wbu1 = Wu[(size_t)(n * 2 + 1) * 64 + lane];
            tap_issue(g0, Xu, ol0[n], ol0[27 + n], ol0[54 + n], n, d0c, h0c, w0c, kg);
            SB0();
            tap_issue(g1, Xu, ol1[n], ol1[27 + n], ol1[54 + n], n, d1c, h1c, w1c, kg);
            SB0();
            union { uint4 u; short8 s; } b0, b1;
            b0.u = wbu0; b1.u = wbu1;
            tap_consume(g0, b0.s, b1.s, acc00, acc01);
            tap_consume(g1, b0.s, b1.s, acc10, acc11);
        }
    }

    // D layout: col = lane&15 -> oc, row = kg*4+reg -> pos
    const int pb0 = p0 + kg * 4;
    const int pb1 = p0 + 16 + kg * 4;
    *(f32x4*)&out[(size_t)row        * SPATIAL + pb0] = acc00;
    *(f32x4*)&out[(size_t)(16 + row) * SPATIAL + pb0] = acc01;
    *(f32x4*)&out[(size_t)row        * SPATIAL + pb1] = acc10;
    *(f32x4*)&out[(size_t)(16 + row) * SPATIAL + pb1] = acc11;
}

// ----------------------------------------------------------------------------
extern "C" void kernel_launch(void* const* d_in, const int* in_sizes, int n_in,
                              void* d_out, int out_size, void* d_ws, size_t ws_size,
                              hipStream_t stream)
{
    const float* x     = (const float*)d_in[0];
    const float* w_off = (const float*)d_in[1];
    const float* w_def = (const float*)d_in[2];
    float* out = (float*)d_out;

    unsigned short* Bp2 = (unsigned short*)((char*)d_ws);
    unsigned short* wpk = (unsigned short*)((char*)d_ws + OFF_WPK);
    unsigned short* xT  = (unsigned short*)((char*)d_ws + OFF_XT);

    wprep2_kernel<<<(BP2_ELEMS + 255) / 256, 256, 0, stream>>>(w_off, Bp2);
    wdefprep_kernel<<<(WPK_ELEMS + 255) / 256, 256, 0, stream>>>(w_def, wpk);
    xtrans_kernel<<<SPATIAL / 64, 256, 0, stream>>>(x, xT);
    fused_deform9<<<SPATIAL / 64, 128, 0, stream>>>(xT, Bp2, wpk, out);
}

// Round 15
// 118.419 us; speedup vs baseline: 1.5808x; 1.0464x over previous
//
#include <hip/hip_runtime.h>

typedef __attribute__((ext_vector_type(8))) short  short8;
typedef __attribute__((ext_vector_type(4))) float  f32x4;
typedef __attribute__((ext_vector_type(2))) float  f32x2;

#define CIN 32
#define COUT 32
#define DD 32
#define HH 48
#define WW 48
#define NTAP 27
#define SPATIAL (DD*HH*WW)          // 73728

// ---- ws layout (bytes) ----
#define BP2_ELEMS (27*6*64*8)                       // conv B-pack: 82944
#define OFF_WPK   ((size_t)BP2_ELEMS*2)             // 165888
#define WPK_ELEMS (27*2*64*8)                       // einsum B-pack: 27648
#define OFF_XT    (OFF_WPK + (size_t)WPK_ELEMS*2)   // 221184 (16B aligned)
// xT bf16: 4,718,592 B -> total ~4.94 MB

#define SB0() __builtin_amdgcn_sched_barrier(0)

__device__ __forceinline__ unsigned short f2bf(float f) {
    union { float f; unsigned u; } v; v.f = f;
    unsigned r = v.u + 0x7FFFu + ((v.u >> 16) & 1u);   // RNE
    return (unsigned short)(r >> 16);
}
__device__ __forceinline__ float bitsf(unsigned u) {
    union { unsigned u; float f; } v; v.u = u; return v.f;
}

// ---------------------------------------------------------------- prep kernels
// conv B-pack: Bp2[((n*6+j)*64+lane)*8+e] = bf16(w_off[j*16+col][kg*8+e][n])
__global__ __launch_bounds__(256) void wprep2_kernel(
        const float* __restrict__ w_off, unsigned short* __restrict__ Bp2)
{
    int i = blockIdx.x * 256 + threadIdx.x;
    if (i >= BP2_ELEMS) return;
    int e    = i & 7;
    int lane = (i >> 3) & 63;
    int j    = (i >> 9) % 6;
    int n    = i / (512 * 6);
    int col = lane & 15, kg = lane >> 4;
    int oc = j * 16 + col, c = kg * 8 + e;
    float v = (oc < 81) ? w_off[((size_t)oc * CIN + c) * NTAP + n] : 0.f;
    Bp2[i] = f2bf(v);
}

// einsum B-pack: wpk[((n*2+half)*64+lane)*8+e] = bf16(w_def[half*16+col][kg*8+e][n])
__global__ __launch_bounds__(256) void wdefprep_kernel(
        const float* __restrict__ w_def, unsigned short* __restrict__ wpk)
{
    int i = blockIdx.x * 256 + threadIdx.x;
    if (i >= WPK_ELEMS) return;
    int e    = i & 7;
    int lane = (i >> 3) & 63;
    int half = (i >> 9) & 1;
    int n    = i >> 10;
    int kg = lane >> 4, col = lane & 15;
    int c  = kg * 8 + e, oc = half * 16 + col;
    wpk[i] = f2bf(w_def[((size_t)oc * CIN + c) * NTAP + n]);
}

// x transpose: xT[pos][c] bf16 (coalesced read via LDS, 16B stores)
__global__ __launch_bounds__(256) void xtrans_kernel(
        const float* __restrict__ x, unsigned short* __restrict__ xT)
{
    __shared__ float t[CIN][65];
    const int p0 = blockIdx.x * 64;
    const int tid = threadIdx.x;
    const int tx = tid & 63, ty = tid >> 6;
    #pragma unroll
    for (int k = 0; k < 8; ++k) {
        int c = ty + k * 4;
        t[c][tx] = x[(size_t)c * SPATIAL + p0 + tx];
    }
    __syncthreads();
    const int pl = tid >> 2, cg = (tid & 3) * 8;
    short8 v;
    #pragma unroll
    for (int i = 0; i < 8; ++i) v[i] = (short)f2bf(t[cg + i][pl]);
    *(short8*)&xT[((size_t)(p0 + pl)) * 32 + cg] = v;
}

// ---------------------------------------------------------------- gather buf
struct Gath {
    uint4 cw[8];
    float gg[8];
};

__device__ __forceinline__ void tap_issue(
        Gath& tb, const uint4* __restrict__ Xu,
        float od, float oh, float ow,
        int n, int d, int h, int w, int kg)
{
    float rd = (float)(n / 9) - 1.f;
    float rh = (float)((n / 3) % 3) - 1.f;
    float rw = (float)(n % 3) - 1.f;

    float pdp = (float)(d + 1) + rd + od;
    float php = (float)(h + 1) + rh + oh;
    float pwp = (float)(w + 1) + rw + ow;

    float fd = floorf(pdp), fh = floorf(php), fw = floorf(pwp);
    float qd0 = fminf(fmaxf(fd,       0.f), 33.f);
    float qd1 = fminf(fmaxf(fd + 1.f, 0.f), 33.f);
    float qh0 = fminf(fmaxf(fh,       0.f), 49.f);
    float qh1 = fminf(fmaxf(fh + 1.f, 0.f), 49.f);
    float qw0 = fminf(fmaxf(fw,       0.f), 49.f);
    float qw1 = fminf(fmaxf(fw + 1.f, 0.f), 49.f);
    float pcd = fminf(fmaxf(pdp, 0.f), 33.f);
    float pch = fminf(fmaxf(php, 0.f), 49.f);
    float pcw = fminf(fmaxf(pwp, 0.f), 49.f);

    float gd0 = 1.f + (qd0 - pcd), gd1 = 1.f - (qd1 - pcd);
    float gh0 = 1.f + (qh0 - pch), gh1 = 1.f - (qh1 - pch);
    float gw0 = 1.f + (qw0 - pcw), gw1 = 1.f - (qw1 - pcw);
    // pad-corner semantics: zero per-axis gain, clamp index to real range
    gd0 = (qd0 >= 1.f && qd0 <= 32.f) ? gd0 : 0.f;
    gd1 = (qd1 >= 1.f && qd1 <= 32.f) ? gd1 : 0.f;
    gh0 = (qh0 >= 1.f && qh0 <= 48.f) ? gh0 : 0.f;
    gh1 = (qh1 >= 1.f && qh1 <= 48.f) ? gh1 : 0.f;
    gw0 = (qw0 >= 1.f && qw0 <= 48.f) ? gw0 : 0.f;
    gw1 = (qw1 >= 1.f && qw1 <= 48.f) ? gw1 : 0.f;
    int zd0 = (int)fminf(fmaxf(qd0, 1.f), 32.f) - 1;
    int zd1 = (int)fminf(fmaxf(qd1, 1.f), 32.f) - 1;
    int zh0 = (int)fminf(fmaxf(qh0, 1.f), 48.f) - 1;
    int zh1 = (int)fminf(fmaxf(qh1, 1.f), 48.f) - 1;
    int zw0 = (int)fminf(fmaxf(qw0, 1.f), 48.f) - 1;
    int zw1 = (int)fminf(fmaxf(qw1, 1.f), 48.f) - 1;

    int bd0 = zd0 * 2304, bd1 = zd1 * 2304;
    int bh0 = zh0 * 48,   bh1 = zh1 * 48;
    float gdh00 = gd0 * gh0, gdh01 = gd0 * gh1;
    float gdh10 = gd1 * gh0, gdh11 = gd1 * gh1;

    tb.cw[0] = Xu[(size_t)(bd0 + bh0 + zw0) * 4 + kg];
    tb.cw[1] = Xu[(size_t)(bd0 + bh0 + zw1) * 4 + kg];
    tb.cw[2] = Xu[(size_t)(bd0 + bh1 + zw0) * 4 + kg];
    tb.cw[3] = Xu[(size_t)(bd0 + bh1 + zw1) * 4 + kg];
    tb.cw[4] = Xu[(size_t)(bd1 + bh0 + zw0) * 4 + kg];
    tb.cw[5] = Xu[(size_t)(bd1 + bh0 + zw1) * 4 + kg];
    tb.cw[6] = Xu[(size_t)(bd1 + bh1 + zw0) * 4 + kg];
    tb.cw[7] = Xu[(size_t)(bd1 + bh1 + zw1) * 4 + kg];

    tb.gg[0] = gdh00 * gw0;  tb.gg[1] = gdh00 * gw1;
    tb.gg[2] = gdh01 * gw0;  tb.gg[3] = gdh01 * gw1;
    tb.gg[4] = gdh10 * gw0;  tb.gg[5] = gdh10 * gw1;
    tb.gg[6] = gdh11 * gw0;  tb.gg[7] = gdh11 * gw1;
}

__device__ __forceinline__ void tap_consume(
        const Gath& tb, short8 b0, short8 b1, f32x4& acc0, f32x4& acc1)
{
    f32x2 xa0 = {0.f, 0.f}, xa1 = {0.f, 0.f};
    f32x2 xa2 = {0.f, 0.f}, xa3 = {0.f, 0.f};

    #pragma unroll
    for (int e = 0; e < 8; ++e) {
        uint4 cw = tb.cw[e];
        f32x2 g2 = {tb.gg[e], tb.gg[e]};
        f32x2 v0 = {bitsf(cw.x << 16), bitsf(cw.x & 0xFFFF0000u)};
        f32x2 v1 = {bitsf(cw.y << 16), bitsf(cw.y & 0xFFFF0000u)};
        f32x2 v2 = {bitsf(cw.z << 16), bitsf(cw.z & 0xFFFF0000u)};
        f32x2 v3 = {bitsf(cw.w << 16), bitsf(cw.w & 0xFFFF0000u)};
        asm("v_pk_fma_f32 %0, %1, %2, %0" : "+v"(xa0) : "v"(v0), "v"(g2));
        asm("v_pk_fma_f32 %0, %1, %2, %0" : "+v"(xa1) : "v"(v1), "v"(g2));
        asm("v_pk_fma_f32 %0, %1, %2, %0" : "+v"(xa2) : "v"(v2), "v"(g2));
        asm("v_pk_fma_f32 %0, %1, %2, %0" : "+v"(xa3) : "v"(v3), "v"(g2));
    }

    union { unsigned u[4]; short8 s; } av;
    asm("v_cvt_pk_bf16_f32 %0, %1, %2" : "=v"(av.u[0]) : "v"(xa0.x), "v"(xa0.y));
    asm("v_cvt_pk_bf16_f32 %0, %1, %2" : "=v"(av.u[1]) : "v"(xa1.x), "v"(xa1.y));
    asm("v_cvt_pk_bf16_f32 %0, %1, %2" : "=v"(av.u[2]) : "v"(xa2.x), "v"(xa2.y));
    asm("v_cvt_pk_bf16_f32 %0, %1, %2" : "=v"(av.u[3]) : "v"(xa3.x), "v"(xa3.y));

    acc0 = __builtin_amdgcn_mfma_f32_16x16x32_bf16(av.s, b0, acc0, 0, 0, 0);
    acc1 = __builtin_amdgcn_mfma_f32_16x16x32_bf16(av.s, b1, acc1, 0, 0, 0);
}

// ---------------- Fused kernel, M=2 tiles/wave, 3-wave blocks (96 pos)
// 768 blocks = exactly 3 blocks/CU (no tail imbalance); 8 XCDs x 96 blocks.
// Conv-B and einsum-B fragments loaded once per wave per tap, feeding both
// M-tiles' MFMAs (halves B-side L1 line probes vs one-tile waves).
__global__ __launch_bounds__(192, 3) void fused_deform10(
        const unsigned short* __restrict__ xT,    // [SPATIAL][32] bf16
        const unsigned short* __restrict__ Bp2,
        const unsigned short* __restrict__ wpk,
        float* __restrict__ out)                  // [32][SPATIAL] f32
{
    __shared__ float offl[3][2][16][82];          // 31.5 KB (cols 0..80 read)

    // bijective XCD swizzle: 768 blocks = 8 XCDs x 96 contiguous
    const int bid  = (int)blockIdx.x;
    const int sbid = (bid & 7) * 96 + (bid >> 3);

    const int tid  = threadIdx.x;
    const int lane = tid & 63, wv = tid >> 6;     // wv in 0..2
    const int p0   = sbid * 96 + wv * 32;
    const int kg   = lane >> 4;
    const int row  = lane & 15;
    const int pos0 = p0 + row;
    const int pos1 = p0 + 16 + row;
    const int w0c = pos0 % WW, h0c = (pos0 / WW) % HH, d0c = pos0 / (WW * HH);
    const int w1c = pos1 % WW, h1c = (pos1 / WW) % HH, d1c = pos1 / (WW * HH);

    const uint4* Xu = (const uint4*)xT;
    const uint4* Bu = (const uint4*)Bp2;
    const uint4* Wu = (const uint4*)wpk;

    // ---------------- phase 1: offset conv, B shared across 2 tiles ----------
    f32x4 cacc0[6], cacc1[6];
    #pragma unroll
    for (int j = 0; j < 6; ++j) {
        cacc0[j] = (f32x4){0.f, 0.f, 0.f, 0.f};
        cacc1[j] = (f32x4){0.f, 0.f, 0.f, 0.f};
    }

    {
        #pragma unroll 1
        for (int n = 0; n < NTAP; ++n) {
            int td = n / 9, th = (n / 3) % 3, tw = n % 3;
            int dis = (td - 1) * 2304 + (th - 1) * 48 + (tw - 1);
            int v0 = ((unsigned)(d0c + td - 1) < DD) & ((unsigned)(h0c + th - 1) < HH)
                   & ((unsigned)(w0c + tw - 1) < WW);
            int v1 = ((unsigned)(d1c + td - 1) < DD) & ((unsigned)(h1c + th - 1) < HH)
                   & ((unsigned)(w1c + tw - 1) < WW);
            uint4 a0 = Xu[(size_t)(v0 ? pos0 + dis : pos0) * 4 + kg];
            uint4 a1 = Xu[(size_t)(v1 ? pos1 + dis : pos1) * 4 + kg];
            uint4 wt[6];
            #pragma unroll
            for (int j = 0; j < 6; ++j)
                wt[j] = Bu[(size_t)(n * 6 + j) * 64 + lane];
            SB0();
            if (!v0) { a0.x = 0; a0.y = 0; a0.z = 0; a0.w = 0; }
            if (!v1) { a1.x = 0; a1.y = 0; a1.z = 0; a1.w = 0; }
            union { uint4 u; short8 s; } av0, av1, b;
            av0.u = a0; av1.u = a1;
            #pragma unroll
            for (int j = 0; j < 6; ++j) {
                b.u = wt[j];
                cacc0[j] = __builtin_amdgcn_mfma_f32_16x16x32_bf16(av0.s, b.s, cacc0[j], 0, 0, 0);
                cacc1[j] = __builtin_amdgcn_mfma_f32_16x16x32_bf16(av1.s, b.s, cacc1[j], 0, 0, 0);
            }
        }
    }

    // ---------------- phase 2: D-frags -> wave-local LDS ----------------
    // col = j*16+row (only cols < 81 are ever read)
    #pragma unroll
    for (int j = 0; j < 6; ++j) {
        #pragma unroll
        for (int r = 0; r < 4; ++r) {
            int col = j * 16 + row;
            if (col < 81) {
                offl[wv][0][kg * 4 + r][col] = cacc0[j][r];
                offl[wv][1][kg * 4 + r][col] = cacc1[j][r];
            }
        }
    }
    __syncthreads();

    // ---------------- phase 3: gather + einsum, B shared across 2 tiles -------
    const float* ol0 = &offl[wv][0][row][0];
    const float* ol1 = &offl[wv][1][row][0];

    f32x4 acc00 = {0.f, 0.f, 0.f, 0.f}, acc01 = {0.f, 0.f, 0.f, 0.f};
    f32x4 acc10 = {0.f, 0.f, 0.f, 0.f}, acc11 = {0.f, 0.f, 0.f, 0.f};

    {
        Gath g0, g1;
        #pragma unroll 1
        for (int n = 0; n < NTAP; ++n) {
            uint4 wbu0 = Wu[(size_t)(n * 2 + 0) * 64 + lane];
            uint4 wbu1 = Wu[(size_t)(n * 2 + 1) * 64 + lane];
            tap_issue(g0, Xu, ol0[n], ol0[27 + n], ol0[54 + n], n, d0c, h0c, w0c, kg);
            SB0();
            tap_issue(g1, Xu, ol1[n], ol1[27 + n], ol1[54 + n], n, d1c, h1c, w1c, kg);
            SB0();
            union { uint4 u; short8 s; } b0, b1;
            b0.u = wbu0; b1.u = wbu1;
            tap_consume(g0, b0.s, b1.s, acc00, acc01);
            tap_consume(g1, b0.s, b1.s, acc10, acc11);
        }
    }

    // D layout: col = lane&15 -> oc, row = kg*4+reg -> pos
    const int pb0 = p0 + kg * 4;
    const int pb1 = p0 + 16 + kg * 4;
    *(f32x4*)&out[(size_t)row        * SPATIAL + pb0] = acc00;
    *(f32x4*)&out[(size_t)(16 + row) * SPATIAL + pb0] = acc01;
    *(f32x4*)&out[(size_t)row        * SPATIAL + pb1] = acc10;
    *(f32x4*)&out[(size_t)(16 + row) * SPATIAL + pb1] = acc11;
}

// ----------------------------------------------------------------------------
extern "C" void kernel_launch(void* const* d_in, const int* in_sizes, int n_in,
                              void* d_out, int out_size, void* d_ws, size_t ws_size,
                              hipStream_t stream)
{
    const float* x     = (const float*)d_in[0];
    const float* w_off = (const float*)d_in[1];
    const float* w_def = (const float*)d_in[2];
    float* out = (float*)d_out;

    unsigned short* Bp2 = (unsigned short*)((char*)d_ws);
    unsigned short* wpk = (unsigned short*)((char*)d_ws + OFF_WPK);
    unsigned short* xT  = (unsigned short*)((char*)d_ws + OFF_XT);

    wprep2_kernel<<<(BP2_ELEMS + 255) / 256, 256, 0, stream>>>(w_off, Bp2);
    wdefprep_kernel<<<(WPK_ELEMS + 255) / 256, 256, 0, stream>>>(w_def, wpk);
    xtrans_kernel<<<SPATIAL / 64, 256, 0, stream>>>(x, xT);
    fused_deform10<<<SPATIAL / 96, 192, 0, stream>>>(xT, Bp2, wpk, out);
}